// Round 5
// baseline (488.183 us; speedup 1.0000x reference)
//
#include <hip/hip_runtime.h>

#define N_TEX 65536
#define C 16
#define U 4194304
#define ILP 4
#define REP1 16   // gather-diagnostic repeats (push dur > fill's 154us)
#define REP2 6    // write-diagnostic repeats

typedef float    f32x4 __attribute__((ext_vector_type(4)));
typedef _Float16 f16x4 __attribute__((ext_vector_type(4)));

// ---------------------------------------------------------------------------
// Convert fp32 texture (4 MiB) -> fp16 (2 MiB) in d_ws.
// ---------------------------------------------------------------------------
__global__ __launch_bounds__(256) void convert_kernel(
    const f32x4* __restrict__ in, f16x4* __restrict__ out16)
{
    const int i = blockIdx.x * 256 + threadIdx.x;
    f32x4 v = __builtin_nontemporal_load(&in[i]);
    f16x4 h;
    h.x = (_Float16)v.x; h.y = (_Float16)v.y;
    h.z = (_Float16)v.z; h.w = (_Float16)v.w;
    out16[i] = h;
}

// ---------------------------------------------------------------------------
// D1: random gathers + param loads ONLY (no stores). Results kept live via
// asm sink. Index rotated per rep (+9973 rows mod 64K) so each rep issues
// fresh random lines of the same statistical class.
// ---------------------------------------------------------------------------
__global__ __launch_bounds__(256) void diag_gather_kernel(
    const f16x4* __restrict__ tex16, const float* __restrict__ param)
{
    const int NT  = (U * 4) / ILP;
    const int tid = blockIdx.x * 256 + threadIdx.x;
    const int q   = tid & 3;
    float ax = 0.f, ay = 0.f, az = 0.f, aw = 0.f;
    for (int rep = 0; rep < REP1; ++rep) {
#pragma unroll
        for (int k = 0; k < ILP; ++k) {
            const float p = param[(tid + k * NT) >> 2];
            const float t = p * (float)(N_TEX - 1);
            const float f = fminf(fmaxf(floorf(t), 0.0f), (float)(N_TEX - 1));
            const float w = t - f;
            const int i0 = ((int)f + rep * 9973) & (N_TEX - 1);
            const int i1 = min(i0 + 1, N_TEX - 1);
            const f16x4 a = tex16[i0 * 4 + q];
            const f16x4 b = tex16[i1 * 4 + q];
            ax += (float)a.x * (1.0f - w) + (float)b.x * w;
            ay += (float)a.y * (1.0f - w) + (float)b.y * w;
            az += (float)a.z * (1.0f - w) + (float)b.z * w;
            aw += (float)a.w * (1.0f - w) + (float)b.w * w;
        }
    }
    asm volatile("" :: "v"(ax), "v"(ay), "v"(az), "v"(aw));
}

// ---------------------------------------------------------------------------
// D2: param loads + full 256 MiB coalesced stores, texture index forced into
// a 4 KiB L1-hot range (no random gather cost).
// ---------------------------------------------------------------------------
__global__ __launch_bounds__(256) void diag_write_kernel(
    const f16x4* __restrict__ tex16, const float* __restrict__ param,
    f32x4* __restrict__ outw)
{
    const int NT  = (U * 4) / ILP;
    const int tid = blockIdx.x * 256 + threadIdx.x;
    const int q   = tid & 3;
    for (int rep = 0; rep < REP2; ++rep) {
#pragma unroll
        for (int k = 0; k < ILP; ++k) {
            const float p = param[(tid + k * NT) >> 2];
            const float t = p * (float)(N_TEX - 1);
            const float f = fminf(fmaxf(floorf(t), 0.0f), (float)(N_TEX - 1));
            const float w = t - f;
            const int i0 = threadIdx.x & 63;   // 64 rows = 4 KiB: L1-hot
            const int i1 = i0 + 1;
            const f16x4 a = tex16[i0 * 4 + q];
            const f16x4 b = tex16[i1 * 4 + q];
            f32x4 r;
            r.x = (float)a.x * (1.0f - w) + (float)b.x * w;
            r.y = (float)a.y * (1.0f - w) + (float)b.y * w;
            r.z = (float)a.z * (1.0f - w) + (float)b.z * w;
            r.w = (float)a.w * (1.0f - w) + (float)b.w * w;
            __builtin_nontemporal_store(r, &outw[tid + k * NT]);
        }
    }
}

// ---------------------------------------------------------------------------
// Real sampler (unchanged from R4) — runs LAST so d_out is correct.
// ---------------------------------------------------------------------------
__global__ __launch_bounds__(256) void sampler1d_kernel(
    const f16x4* __restrict__ tex16, const float* __restrict__ param,
    f32x4* __restrict__ out)
{
    const int NT  = (U * 4) / ILP;
    const int tid = blockIdx.x * 256 + threadIdx.x;
    const int q   = tid & 3;

    float p[ILP];
#pragma unroll
    for (int k = 0; k < ILP; ++k)
        p[k] = __builtin_nontemporal_load(&param[(tid + k * NT) >> 2]);

    float w[ILP];
    f16x4 a[ILP], b[ILP];
#pragma unroll
    for (int k = 0; k < ILP; ++k) {
        const float t = p[k] * (float)(N_TEX - 1);
        float f = floorf(t);
        f = fminf(fmaxf(f, 0.0f), (float)(N_TEX - 1));
        const int i0 = (int)f;
        const int i1 = min(i0 + 1, N_TEX - 1);
        w[k] = t - f;
        a[k] = tex16[i0 * 4 + q];
        b[k] = tex16[i1 * 4 + q];
    }

#pragma unroll
    for (int k = 0; k < ILP; ++k) {
        const float wk = w[k], iw = 1.0f - wk;
        f32x4 r;
        r.x = (float)a[k].x * iw + (float)b[k].x * wk;
        r.y = (float)a[k].y * iw + (float)b[k].y * wk;
        r.z = (float)a[k].z * iw + (float)b[k].z * wk;
        r.w = (float)a[k].w * iw + (float)b[k].w * wk;
        __builtin_nontemporal_store(r, &out[tid + k * NT]);
    }
}

extern "C" void kernel_launch(void* const* d_in, const int* in_sizes, int n_in,
                              void* d_out, int out_size, void* d_ws, size_t ws_size,
                              hipStream_t stream) {
    const f32x4* tex32 = (const f32x4*)d_in[0];
    const float* param = (const float*)d_in[1];
    f32x4*       out   = (f32x4*)d_out;
    f16x4*       tex16 = (f16x4*)d_ws;                         // 2 MiB
    f32x4*       diagw = (f32x4*)((char*)d_ws + (4u << 20));   // +256 MiB

    const int total_thr = (U * 4) / ILP;

    convert_kernel<<<(N_TEX * C / 4) / 256, 256, 0, stream>>>(tex32, tex16);

    // Diagnostics (only if workspace is big enough; ws_size is fixed per
    // session so this branch is deterministic).
    if (ws_size >= (4ull << 20) + (256ull << 20)) {
        diag_gather_kernel<<<total_thr / 256, 256, 0, stream>>>(tex16, param);
        diag_write_kernel <<<total_thr / 256, 256, 0, stream>>>(tex16, param, diagw);
    }

    sampler1d_kernel<<<total_thr / 256, 256, 0, stream>>>(tex16, param, out);
}

// Round 6
// 84.513 us; speedup vs baseline: 5.7765x; 5.7765x over previous
//
#include <hip/hip_runtime.h>

#define N_TEX 65536
#define C 16
#define U 4194304
#define ILP 4

typedef float    f32x4 __attribute__((ext_vector_type(4)));
typedef _Float16 f16x4 __attribute__((ext_vector_type(4)));

// ---------------------------------------------------------------------------
// Convert fp32 texture (4 MiB) -> fp16 (2 MiB) in d_ws.
// ---------------------------------------------------------------------------
__global__ __launch_bounds__(256) void convert_kernel(
    const f32x4* __restrict__ in, f16x4* __restrict__ out16)
{
    const int i = blockIdx.x * 256 + threadIdx.x;
    f32x4 v = __builtin_nontemporal_load(&in[i]);
    f16x4 h;
    h.x = (_Float16)v.x; h.y = (_Float16)v.y;
    h.z = (_Float16)v.z; h.w = (_Float16)v.w;
    out16[i] = h;
}

// ---------------------------------------------------------------------------
// Warm kernel: same grid as the sampler (16,384 x 256) so block b lands on
// the same XCD and pre-loads into that XCD's L2 exactly what sampler block b
// will read:
//   - param slices: sampler block b reads param[b*64 + j + k*1048576],
//     j in [0,64), k in [0,4)  (4 chunks x 256 B)
//   - texture: each XCD's 2048 blocks collectively touch all 2 MiB
//     (block chunk c = b>>3, 1 KiB each)
// Values kept live with an asm sink (no stores -> no L2 pollution).
// ---------------------------------------------------------------------------
__global__ __launch_bounds__(256) void warm_kernel(
    const int* __restrict__ tex16i, const float* __restrict__ param)
{
    const int b = blockIdx.x;
    const int t = threadIdx.x;

    // param: 4 chunks of 64 floats
    const int j = t & 63;
    const int k = t >> 6;
    float pv = param[b * 64 + j + k * 1048576];

    // texture: chunk c = b>>3 covers bytes [c*1024, c*1024+1024)
    const int c = b >> 3;
    int tv = tex16i[c * 256 + t];

    asm volatile("" :: "v"(pv), "v"(tv));
}

// ---------------------------------------------------------------------------
// Sampler (unchanged from R4): 4 lanes per sample, fp16 texture, ILP=4,
// nontemporal param loads + output stores.
// ---------------------------------------------------------------------------
__global__ __launch_bounds__(256) void sampler1d_kernel(
    const f16x4* __restrict__ tex16, const float* __restrict__ param,
    f32x4* __restrict__ out)
{
    const int NT  = (U * 4) / ILP;
    const int tid = blockIdx.x * 256 + threadIdx.x;
    const int q   = tid & 3;

    float p[ILP];
#pragma unroll
    for (int k = 0; k < ILP; ++k)
        p[k] = __builtin_nontemporal_load(&param[(tid + k * NT) >> 2]);

    float w[ILP];
    f16x4 a[ILP], b[ILP];
#pragma unroll
    for (int k = 0; k < ILP; ++k) {
        const float t = p[k] * (float)(N_TEX - 1);
        float f = floorf(t);
        f = fminf(fmaxf(f, 0.0f), (float)(N_TEX - 1));
        const int i0 = (int)f;
        const int i1 = min(i0 + 1, N_TEX - 1);
        w[k] = t - f;
        a[k] = tex16[i0 * 4 + q];
        b[k] = tex16[i1 * 4 + q];
    }

#pragma unroll
    for (int k = 0; k < ILP; ++k) {
        const float wk = w[k], iw = 1.0f - wk;
        f32x4 r;
        r.x = (float)a[k].x * iw + (float)b[k].x * wk;
        r.y = (float)a[k].y * iw + (float)b[k].y * wk;
        r.z = (float)a[k].z * iw + (float)b[k].z * wk;
        r.w = (float)a[k].w * iw + (float)b[k].w * wk;
        __builtin_nontemporal_store(r, &out[tid + k * NT]);
    }
}

extern "C" void kernel_launch(void* const* d_in, const int* in_sizes, int n_in,
                              void* d_out, int out_size, void* d_ws, size_t ws_size,
                              hipStream_t stream) {
    const f32x4* tex32 = (const f32x4*)d_in[0];
    const float* param = (const float*)d_in[1];
    f32x4*       out   = (f32x4*)d_out;
    f16x4*       tex16 = (f16x4*)d_ws;     // 2 MiB scratch

    const int total_thr = (U * 4) / ILP;   // 4,194,304 -> 16,384 blocks

    convert_kernel<<<(N_TEX * C / 4) / 256, 256, 0, stream>>>(tex32, tex16);
    warm_kernel<<<total_thr / 256, 256, 0, stream>>>((const int*)tex16, param);
    sampler1d_kernel<<<total_thr / 256, 256, 0, stream>>>(tex16, param, out);
}